// Round 11
// baseline (66.133 us; speedup 1.0000x reference)
//
#include <hip/hip_runtime.h>

#define T_ 16
#define B_ 32
#define N_ 4096
#define NT 20
#define F_ 25
#define H_ 8
#define HID_ 128
#define PSTR 9               // padded LDS pool stride
#define SEGF_ (NT*H_)        // 160
#define BT 768               // 12 waves/block; 2 blocks/CU -> 24 waves/CU
#define NWAVE 12
#define FULLCH 5             // 5 full chunks of 768 pts + 256-pt tail
#define CF (BT*F_)           // 19200 floats per full chunk
#define WSL 1600             // floats per wave slice (64 pts x 25)

typedef __attribute__((address_space(1))) const void GV;
typedef __attribute__((address_space(3))) void LV;

__device__ __forceinline__ void g2l16(const float* g, float* l) {
  __builtin_amdgcn_global_load_lds((GV*)g, (LV*)l, 16, 0, 0);
}
__device__ __forceinline__ void g2l4(const float* g, float* l) {
  __builtin_amdgcn_global_load_lds((GV*)g, (LV*)l, 4, 0, 0);
}

// bf16 pack/unpack (values nonneg finite: relu outputs)
__device__ __forceinline__ unsigned f2bf(float x) {
  unsigned u = __float_as_uint(x);
  u += 0x7fffu + ((u >> 16) & 1u);
  return u >> 16;
}
__device__ __forceinline__ float bf2f(unsigned s) { return __uint_as_float(s << 16); }

// Tiny fully-unrolled MLP layer (s_load weights — R9 showed LDS-cached weights
// are slower and marginal s_load cost is ~0).
template<int NI>
__device__ __forceinline__ void layer(const float* in, const float* __restrict__ W,
                                      const float* __restrict__ b, float* out) {
#pragma unroll
  for (int j = 0; j < H_; j++) {
    float a = b[j];
#pragma unroll
    for (int f = 0; f < NI; f++) a = fmaf(in[f], W[f*H_ + j], a);
    out[j] = fmaxf(a, 0.0f);
  }
}

// R10 structure (wave-private staging, per-wave vmcnt/lgkm sync, free-running
// waves) at 24 waves/CU. One block per (t,b), 12 waves, 5 full chunks + tail.
extern "C" __global__ __launch_bounds__(BT, 6)
void kFused(const float* __restrict__ pts,
            const float* __restrict__ W1, const float* __restrict__ b1,
            const float* __restrict__ W2, const float* __restrict__ b2,
            const float* __restrict__ W3, const float* __restrict__ b3,
            const float* __restrict__ W4, const float* __restrict__ b4,
            const float* __restrict__ W5, const float* __restrict__ b5,
            const float* __restrict__ W6, const float* __restrict__ b6,
            const float* __restrict__ Wout, const float* __restrict__ bout,
            float* __restrict__ out)
{
  __shared__ float xs[NWAVE*WSL];     // 76.8 KB: 12 wave-private 6.4 KB slices
  __shared__ int lp1[NT*PSTR];        // pools: nonneg float bits, int max == float max
  __shared__ int lp2[NT*PSTR];
  const int tid  = threadIdx.x;
  const int wid  = tid >> 6;
  const int lane = tid & 63;
  const int tb = blockIdx.x;
  if (tid < NT*PSTR) { lp1[tid] = 0; lp2[tid] = 0; }
  __syncthreads();                    // pools zeroed before any atomics

  const float* base = pts + (size_t)tb * (N_*F_);
  float* lw = xs + wid*WSL;           // this wave's private slice

  // Wave-private DMA: instr k -> uniform base + lane*16B; lane l's point data
  // = slice floats [l*25, l*25+25), loaded and read by this wave only.
#define ISSUE(S)                                                         \
  {                                                                      \
    const float* gw = base + (S)*CF + wid*WSL;                           \
    _Pragma("unroll")                                                    \
    for (int k = 0; k < 6; k++)                                          \
      g2l16(gw + k*256 + lane*4, lw + k*256 + lane*4);                   \
    g2l4(gw + 1536 + lane, lw + 1536 + lane);                            \
  }
  // tail chunk: 256 pts at offset 5*CF, waves 0..3 only (caller guards wid<4)
#define ISSUE_TAIL()                                                     \
  {                                                                      \
    const float* gw = base + FULLCH*CF + wid*WSL;                        \
    _Pragma("unroll")                                                    \
    for (int k = 0; k < 6; k++)                                          \
      g2l16(gw + k*256 + lane*4, lw + k*256 + lane*4);                   \
    g2l4(gw + 1536 + lane, lw + 1536 + lane);                            \
  }

  uint4 h3p[FULLCH+1];                 // bf16x8 per point — literal indices only
  int   tyv[FULLCH+1];
  tyv[FULLCH] = -1;                    // default for waves with no tail point

  ISSUE(0)

  // BODY: wait own DMA, xv->regs, drain ds, prefetch next, compute, pool.
#define PH1BODY(S)                                                       \
  {                                                                      \
    asm volatile("s_waitcnt vmcnt(0)" ::: "memory");                     \
    __builtin_amdgcn_sched_barrier(0);                                   \
    float xv[F_];                                                        \
    _Pragma("unroll")                                                    \
    for (int f = 0; f < F_; f++) xv[f] = lw[lane*F_ + f];                \
    asm volatile("s_waitcnt lgkmcnt(0)" ::: "memory");                   \
    __builtin_amdgcn_sched_barrier(0);                                   \
    if ((S) < FULLCH-1) ISSUE((S)+1)                                     \
    else if ((S) == FULLCH-1) { if (wid < 4) ISSUE_TAIL() }              \
    int ty = 0; float best = xv[4];                                      \
    _Pragma("unroll")                                                    \
    for (int k = 1; k < NT; k++)                                         \
      if (xv[4+k] > best) { best = xv[4+k]; ty = k; }                    \
    const bool valid = (xv[F_-1] != 0.0f);                               \
    float t1[H_], t2[H_];                                                \
    layer<F_>(xv, W1, b1, t1);                                           \
    layer<H_>(t1, W2, b2, t2);                                           \
    layer<H_>(t2, W3, b3, t1);                                           \
    if (!valid) {                                                        \
      _Pragma("unroll")                                                  \
      for (int j = 0; j < H_; j++) t1[j] = 0.0f;                         \
    }                                                                    \
    h3p[S].x = f2bf(t1[0]) | (f2bf(t1[1]) << 16);                        \
    h3p[S].y = f2bf(t1[2]) | (f2bf(t1[3]) << 16);                        \
    h3p[S].z = f2bf(t1[4]) | (f2bf(t1[5]) << 16);                        \
    h3p[S].w = f2bf(t1[6]) | (f2bf(t1[7]) << 16);                        \
    tyv[S] = valid ? ty : -1;                                            \
    if (valid) {                                                         \
      _Pragma("unroll")                                                  \
      for (int j = 0; j < H_; j++)                                       \
        atomicMax(&lp1[ty*PSTR + j], __float_as_int(t1[j]));             \
    }                                                                    \
  }

  PH1BODY(0) PH1BODY(1) PH1BODY(2) PH1BODY(3) PH1BODY(4)
  if (wid < 4) PH1BODY(5)              // tail: wave-uniform branch

  __syncthreads();                     // pool1 final (all waves' atomics visible)

#define PH2(S)                                                           \
  {                                                                      \
    const int ty = tyv[S];                                               \
    if (ty >= 0) {                                                       \
      float x16[2*H_];                                                   \
      x16[0] = bf2f(h3p[S].x & 0xffffu); x16[1] = bf2f(h3p[S].x >> 16);  \
      x16[2] = bf2f(h3p[S].y & 0xffffu); x16[3] = bf2f(h3p[S].y >> 16);  \
      x16[4] = bf2f(h3p[S].z & 0xffffu); x16[5] = bf2f(h3p[S].z >> 16);  \
      x16[6] = bf2f(h3p[S].w & 0xffffu); x16[7] = bf2f(h3p[S].w >> 16);  \
      _Pragma("unroll")                                                  \
      for (int j = 0; j < H_; j++)                                       \
        x16[H_+j] = __int_as_float(lp1[ty*PSTR + j]);                    \
      float t1[H_], t2[H_];                                              \
      layer<2*H_>(x16, W4, b4, t1);                                      \
      layer<H_>(t1, W5, b5, t2);                                         \
      layer<H_>(t2, W6, b6, t1);                                         \
      _Pragma("unroll")                                                  \
      for (int j = 0; j < H_; j++)                                       \
        atomicMax(&lp2[ty*PSTR + j], __float_as_int(t1[j]));             \
    }                                                                    \
  }

  PH2(0) PH2(1) PH2(2) PH2(3) PH2(4) PH2(5)

  __syncthreads();                     // pool2 final

  // ---- Phase 3: out[tb,:] = relu(pooled2 @ Wout + bout) ----
  if (tid < HID_) {
    float a = bout[tid];
#pragma unroll 4
    for (int k = 0; k < SEGF_; k++) {
      const float v = __int_as_float(lp2[(k >> 3)*PSTR + (k & 7)]);
      a = fmaf(v, Wout[k*HID_ + tid], a);
    }
    out[tb*HID_ + tid] = fmaxf(a, 0.0f);
  }
#undef ISSUE
#undef ISSUE_TAIL
#undef PH1BODY
#undef PH2
}

extern "C" void kernel_launch(void* const* d_in, const int* in_sizes, int n_in,
                              void* d_out, int out_size, void* d_ws, size_t ws_size,
                              hipStream_t stream) {
  const float* pts  = (const float*)d_in[0];
  const float* W1   = (const float*)d_in[1];  const float* b1 = (const float*)d_in[2];
  const float* W2   = (const float*)d_in[3];  const float* b2 = (const float*)d_in[4];
  const float* W3   = (const float*)d_in[5];  const float* b3 = (const float*)d_in[6];
  const float* W4   = (const float*)d_in[7];  const float* b4 = (const float*)d_in[8];
  const float* W5   = (const float*)d_in[9];  const float* b5 = (const float*)d_in[10];
  const float* W6   = (const float*)d_in[11]; const float* b6 = (const float*)d_in[12];
  const float* Wout = (const float*)d_in[13]; const float* bout = (const float*)d_in[14];
  float* out = (float*)d_out;

  kFused<<<T_*B_, BT, 0, stream>>>(pts, W1, b1, W2, b2, W3, b3,
                                   W4, b4, W5, b5, W6, b6, Wout, bout, out);
}

// Round 12
// 62.442 us; speedup vs baseline: 1.0591x; 1.0591x over previous
//
#include <hip/hip_runtime.h>

#define T_ 16
#define B_ 32
#define N_ 4096
#define NT 20
#define F_ 25
#define H_ 8
#define HID_ 128
#define PSTR 9               // padded LDS pool stride
#define SEGF_ (NT*H_)        // 160
#define BT 512               // threads per block; one block per (t,b)
#define NSUB (N_/BT)         // 8 chunks of 512 points
#define CF (BT*F_)           // 12800 floats per chunk
#define WSL 1600             // floats per wave slice (64 pts x 25)

typedef __attribute__((address_space(1))) const void GV;
typedef __attribute__((address_space(3))) void LV;

__device__ __forceinline__ void g2l16(const float* g, float* l) {
  __builtin_amdgcn_global_load_lds((GV*)g, (LV*)l, 16, 0, 0);
}
__device__ __forceinline__ void g2l4(const float* g, float* l) {
  __builtin_amdgcn_global_load_lds((GV*)g, (LV*)l, 4, 0, 0);
}

__device__ __forceinline__ float bf2f(unsigned s) { return __uint_as_float(s << 16); }

// packed bf16 convert: dst = {lo16: bf16(lo), hi16: bf16(hi)}, RNE
__device__ __forceinline__ unsigned cvtpk_bf16(float lo, float hi) {
  unsigned r;
  asm("v_cvt_pk_bf16_f32 %0, %1, %2" : "=v"(r) : "v"(lo), "v"(hi));
  return r;
}

// packed fp32 FMA: acc.{x,y} += a * W[{0,1}]; weight pair rides as one SGPR-pair
// operand (uniform address -> s_load), input broadcast via {a,a} VGPR pair.
__device__ __forceinline__ void pkfma(float2& acc, float a,
                                      const float* __restrict__ wp) {
  const float2 w = *(const float2*)wp;
  float2 a2; a2.x = a; a2.y = a;
  asm("v_pk_fma_f32 %0, %1, %2, %0" : "+v"(acc) : "v"(a2), "s"(w));
}

// out = relu(in @ W + b), W (NI x 8) row-major; 4 packed accumulator pairs.
// Chain order per output j identical to scalar version -> bit-identical result.
template<int NI>
__device__ __forceinline__ void layerP(const float* in, const float* __restrict__ W,
                                       const float* __restrict__ b, float* out) {
  float2 acc[4];
#pragma unroll
  for (int jp = 0; jp < 4; jp++) acc[jp] = *(const float2*)&b[jp*2];
#pragma unroll
  for (int f = 0; f < NI; f++) {
#pragma unroll
    for (int jp = 0; jp < 4; jp++) pkfma(acc[jp], in[f], &W[f*H_ + jp*2]);
  }
#pragma unroll
  for (int jp = 0; jp < 4; jp++) {
    out[jp*2]   = fmaxf(acc[jp].x, 0.0f);
    out[jp*2+1] = fmaxf(acc[jp].y, 0.0f);
  }
}

// layer-8 with bias pairs taken from LDS (per-type precomputed contribution).
__device__ __forceinline__ void layerPc(const float* in, const float* __restrict__ W,
                                        const float* ctbp, float* out) {
  float2 acc[4];
#pragma unroll
  for (int jp = 0; jp < 4; jp++) acc[jp] = *(const float2*)&ctbp[jp*2];
#pragma unroll
  for (int f = 0; f < H_; f++) {
#pragma unroll
    for (int jp = 0; jp < 4; jp++) pkfma(acc[jp], in[f], &W[f*H_ + jp*2]);
  }
#pragma unroll
  for (int jp = 0; jp < 4; jp++) {
    out[jp*2]   = fmaxf(acc[jp].x, 0.0f);
    out[jp*2+1] = fmaxf(acc[jp].y, 0.0f);
  }
}

// R10 structure (wave-private staging, per-wave vmcnt/lgkm sync, free-running
// waves, 2 blocks/CU). R12: pk_fma math, cvt_pk_bf16 pack, per-type ctb
// precompute replaces the pooled half of layer 4 (-64 FMA/point).
extern "C" __global__ __launch_bounds__(BT, 4)
void kFused(const float* __restrict__ pts,
            const float* __restrict__ W1, const float* __restrict__ b1,
            const float* __restrict__ W2, const float* __restrict__ b2,
            const float* __restrict__ W3, const float* __restrict__ b3,
            const float* __restrict__ W4, const float* __restrict__ b4,
            const float* __restrict__ W5, const float* __restrict__ b5,
            const float* __restrict__ W6, const float* __restrict__ b6,
            const float* __restrict__ Wout, const float* __restrict__ bout,
            float* __restrict__ out)
{
  __shared__ float xs[8*WSL];         // 51.2 KB: 8 wave-private 6.4 KB slices
  __shared__ int lp1[NT*PSTR];        // pools: nonneg float bits, int max == float max
  __shared__ int lp2[NT*PSTR];
  __shared__ float ctb[NT*H_];        // per-type layer-4 pooled contribution
  const int tid  = threadIdx.x;
  const int wid  = tid >> 6;
  const int lane = tid & 63;
  const int tb = blockIdx.x;
  if (tid < NT*PSTR) { lp1[tid] = 0; lp2[tid] = 0; }
  __syncthreads();                    // pools zeroed before any atomics

  const float* base = pts + (size_t)tb * (N_*F_);
  float* lw = xs + wid*WSL;           // this wave's private slice

#define ISSUE(S)                                                         \
  {                                                                      \
    const float* gw = base + (S)*CF + wid*WSL;                           \
    _Pragma("unroll")                                                    \
    for (int k = 0; k < 6; k++)                                          \
      g2l16(gw + k*256 + lane*4, lw + k*256 + lane*4);                   \
    g2l4(gw + 1536 + lane, lw + 1536 + lane);                            \
  }

  uint4 h3p[NSUB];                     // bf16x8 per point — literal indices only
  int   tyv[NSUB];

  ISSUE(0)

#define PH1(S)                                                           \
  {                                                                      \
    asm volatile("s_waitcnt vmcnt(0)" ::: "memory");                     \
    __builtin_amdgcn_sched_barrier(0);                                   \
    float xv[F_];                                                        \
    _Pragma("unroll")                                                    \
    for (int f = 0; f < F_; f++) xv[f] = lw[lane*F_ + f];                \
    asm volatile("s_waitcnt lgkmcnt(0)" ::: "memory");                   \
    __builtin_amdgcn_sched_barrier(0);                                   \
    if ((S) < NSUB-1) ISSUE((S)+1)                                       \
    int ty = 0; float best = xv[4];                                      \
    _Pragma("unroll")                                                    \
    for (int k = 1; k < NT; k++)                                         \
      if (xv[4+k] > best) { best = xv[4+k]; ty = k; }                    \
    const bool valid = (xv[F_-1] != 0.0f);                               \
    float t1[H_], t2[H_];                                                \
    layerP<F_>(xv, W1, b1, t1);                                          \
    layerP<H_>(t1, W2, b2, t2);                                          \
    layerP<H_>(t2, W3, b3, t1);                                          \
    if (!valid) {                                                        \
      _Pragma("unroll")                                                  \
      for (int j = 0; j < H_; j++) t1[j] = 0.0f;                         \
    }                                                                    \
    h3p[S].x = cvtpk_bf16(t1[0], t1[1]);                                 \
    h3p[S].y = cvtpk_bf16(t1[2], t1[3]);                                 \
    h3p[S].z = cvtpk_bf16(t1[4], t1[5]);                                 \
    h3p[S].w = cvtpk_bf16(t1[6], t1[7]);                                 \
    tyv[S] = valid ? ty : -1;                                            \
    if (valid) {                                                         \
      _Pragma("unroll")                                                  \
      for (int j = 0; j < H_; j++)                                       \
        atomicMax(&lp1[ty*PSTR + j], __float_as_int(t1[j]));             \
    }                                                                    \
  }

  PH1(0) PH1(1) PH1(2) PH1(3) PH1(4) PH1(5) PH1(6) PH1(7)

  __syncthreads();                     // pool1 final (all waves' atomics visible)

  // per-type pooled contribution for layer 4: ctb[ty][j] = b4[j] + pool1[ty]@W4b
  if (tid < NT*H_) {
    const int cty = tid >> 3, cj = tid & 7;
    float a = b4[cj];
#pragma unroll
    for (int k = 0; k < H_; k++)
      a = fmaf(__int_as_float(lp1[cty*PSTR + k]), W4[(H_+k)*H_ + cj], a);
    ctb[tid] = a;
  }
  __syncthreads();

#define PH2(S)                                                           \
  {                                                                      \
    const int ty = tyv[S];                                               \
    if (ty >= 0) {                                                       \
      float x8[H_];                                                      \
      x8[0] = bf2f(h3p[S].x & 0xffffu); x8[1] = bf2f(h3p[S].x >> 16);    \
      x8[2] = bf2f(h3p[S].y & 0xffffu); x8[3] = bf2f(h3p[S].y >> 16);    \
      x8[4] = bf2f(h3p[S].z & 0xffffu); x8[5] = bf2f(h3p[S].z >> 16);    \
      x8[6] = bf2f(h3p[S].w & 0xffffu); x8[7] = bf2f(h3p[S].w >> 16);    \
      float t1[H_], t2[H_];                                              \
      layerPc(x8, W4, &ctb[ty*H_], t1);                                  \
      layerP<H_>(t1, W5, b5, t2);                                        \
      layerP<H_>(t2, W6, b6, t1);                                        \
      _Pragma("unroll")                                                  \
      for (int j = 0; j < H_; j++)                                       \
        atomicMax(&lp2[ty*PSTR + j], __float_as_int(t1[j]));             \
    }                                                                    \
  }

  PH2(0) PH2(1) PH2(2) PH2(3) PH2(4) PH2(5) PH2(6) PH2(7)

  __syncthreads();                     // pool2 final

  // ---- Phase 3: out[tb,:] = relu(pooled2 @ Wout + bout) ----
  if (tid < HID_) {
    float a = bout[tid];
#pragma unroll 4
    for (int k = 0; k < SEGF_; k++) {
      const float v = __int_as_float(lp2[(k >> 3)*PSTR + (k & 7)]);
      a = fmaf(v, Wout[k*HID_ + tid], a);
    }
    out[tb*HID_ + tid] = fmaxf(a, 0.0f);
  }
#undef ISSUE
#undef PH1
#undef PH2
}

extern "C" void kernel_launch(void* const* d_in, const int* in_sizes, int n_in,
                              void* d_out, int out_size, void* d_ws, size_t ws_size,
                              hipStream_t stream) {
  const float* pts  = (const float*)d_in[0];
  const float* W1   = (const float*)d_in[1];  const float* b1 = (const float*)d_in[2];
  const float* W2   = (const float*)d_in[3];  const float* b2 = (const float*)d_in[4];
  const float* W3   = (const float*)d_in[5];  const float* b3 = (const float*)d_in[6];
  const float* W4   = (const float*)d_in[7];  const float* b4 = (const float*)d_in[8];
  const float* W5   = (const float*)d_in[9];  const float* b5 = (const float*)d_in[10];
  const float* W6   = (const float*)d_in[11]; const float* b6 = (const float*)d_in[12];
  const float* Wout = (const float*)d_in[13]; const float* bout = (const float*)d_in[14];
  float* out = (float*)d_out;

  kFused<<<T_*B_, BT, 0, stream>>>(pts, W1, b1, W2, b2, W3, b3,
                                   W4, b4, W5, b5, W6, b6, Wout, bout, out);
}